// Round 1
// baseline (848.423 us; speedup 1.0000x reference)
//
#include <hip/hip_runtime.h>
#include <hip/hip_bf16.h>

#define NROWS 8192
#define DDIM 768

typedef short short8 __attribute__((ext_vector_type(8)));   // 8 x bf16 (4 VGPRs)
typedef float floatx4 __attribute__((ext_vector_type(4)));  // MFMA C/D

// ---------------------------------------------------------------------------
// Kernel 1: row-normalize features (fp32 in) -> bf16 normalized rows
// one block (256 thr) per row; each thread handles 3 of 768 columns
// ---------------------------------------------------------------------------
__global__ __launch_bounds__(256) void normalize_k(const float* __restrict__ f,
                                                   __hip_bfloat16* __restrict__ fn) {
    const int row = blockIdx.x;
    const int t = threadIdx.x;
    const float* fr = f + (size_t)row * DDIM;
    float v0 = fr[t];
    float v1 = fr[t + 256];
    float v2 = fr[t + 512];
    float ss = v0 * v0 + v1 * v1 + v2 * v2;
#pragma unroll
    for (int m = 32; m; m >>= 1) ss += __shfl_xor(ss, m, 64);
    __shared__ float wsum[4];
    if ((t & 63) == 0) wsum[t >> 6] = ss;
    __syncthreads();
    float tot = wsum[0] + wsum[1] + wsum[2] + wsum[3];
    float inv = 1.0f / fmaxf(sqrtf(tot), 1e-8f);
    __hip_bfloat16* o = fn + (size_t)row * DDIM;
    o[t]       = __float2bfloat16(v0 * inv);
    o[t + 256] = __float2bfloat16(v1 * inv);
    o[t + 512] = __float2bfloat16(v2 * inv);
}

// ---------------------------------------------------------------------------
// Kernel 2: fused bf16 GEMM (s = 10 * fn fn^T) + masked row reductions.
// m97-style: 128x128 C tile, BK=32, global_load_lds width 16, mfma 16x16x32.
// Each block: 128 rows x 512 cols (4 col-tiles), row partials in LDS,
// 4 global atomicAdds per row at the end.
// grid = (16 col-chunks, 64 row-tiles), block = 256 (4 waves, 2x2).
// ---------------------------------------------------------------------------
__global__ __launch_bounds__(256) void ntxent_main(
        const __hip_bfloat16* __restrict__ fn,
        const float* __restrict__ pmask,
        const float* __restrict__ nmask,
        float* __restrict__ negG, float* __restrict__ sG,
        float* __restrict__ pG, float* __restrict__ qG) {
    __shared__ __hip_bfloat16 As[128 * 32];   // 8 KB
    __shared__ __hip_bfloat16 Bs[128 * 32];   // 8 KB
    __shared__ float rowacc[128][4];          // 2 KB: neg, S, P, Q per row

    const int t = threadIdx.x;
    const int lane = t & 63;
    const int wv = t >> 6;
    const int wr = wv >> 1;          // wave row (0..1) -> 64 C-rows
    const int wc = wv & 1;           // wave col (0..1) -> 64 C-cols
    const int q  = lane >> 4;        // quad 0..3
    const int cl = lane & 15;        // col-in-tile lane
    const int rowBase  = blockIdx.y * 128;
    const int colChunk = blockIdx.x * 512;

    if (t < 128) {
        rowacc[t][0] = 0.f; rowacc[t][1] = 0.f;
        rowacc[t][2] = 0.f; rowacc[t][3] = 0.f;
    }

    // staging map: thread t loads 16 B -> LDS byte offset t*16 (wave-uniform
    // base + lane*16, as global_load_lds requires). Tile is [128 rows][32 k].
    const int sRow = t >> 2;          // 0..63 (+64 on second iter)
    const int sCol = (t & 3) * 8;     // k-element offset

    for (int j2 = 0; j2 < 4; ++j2) {
        const int colBase = colChunk + j2 * 128;
        floatx4 acc[4][4];
#pragma unroll
        for (int r = 0; r < 4; ++r)
#pragma unroll
            for (int c = 0; c < 4; ++c)
                acc[r][c] = (floatx4){0.f, 0.f, 0.f, 0.f};

        for (int k0 = 0; k0 < DDIM; k0 += 32) {
            __syncthreads();   // prior iter's ds_reads done before overwrite
#pragma unroll
            for (int it = 0; it < 2; ++it) {
                const int rr = sRow + it * 64;
                const __hip_bfloat16* ga = fn + (size_t)(rowBase + rr) * DDIM + k0 + sCol;
                const __hip_bfloat16* gb = fn + (size_t)(colBase + rr) * DDIM + k0 + sCol;
                __builtin_amdgcn_global_load_lds(
                    (const __attribute__((address_space(1))) void*)ga,
                    (__attribute__((address_space(3))) void*)&As[rr * 32 + sCol], 16, 0, 0);
                __builtin_amdgcn_global_load_lds(
                    (const __attribute__((address_space(1))) void*)gb,
                    (__attribute__((address_space(3))) void*)&Bs[rr * 32 + sCol], 16, 0, 0);
            }
            __syncthreads();   // compiler drains vmcnt before s_barrier

            short8 af[4], bf[4];
#pragma unroll
            for (int r = 0; r < 4; ++r)
                af[r] = *(const short8*)&As[(wr * 64 + r * 16 + cl) * 32 + q * 8];
#pragma unroll
            for (int c = 0; c < 4; ++c)
                bf[c] = *(const short8*)&Bs[(wc * 64 + c * 16 + cl) * 32 + q * 8];
#pragma unroll
            for (int r = 0; r < 4; ++r)
#pragma unroll
                for (int c = 0; c < 4; ++c)
                    acc[r][c] = __builtin_amdgcn_mfma_f32_16x16x32_bf16(
                        af[r], bf[c], acc[r][c], 0, 0, 0);
        }

        // ---- epilogue for this 128x128 s-tile ----
        // C/D layout: col = lane&15, row = (lane>>4)*4 + reg  [m89/m91]
#pragma unroll
        for (int r = 0; r < 4; ++r) {
#pragma unroll
            for (int i = 0; i < 4; ++i) {
                const int lrow = wr * 64 + r * 16 + q * 4 + i;
                const int grow = rowBase + lrow;
                float aN = 0.f, aS = 0.f, aP = 0.f, aQ = 0.f;
#pragma unroll
                for (int c = 0; c < 4; ++c) {
                    const int gcol = colBase + wc * 64 + c * 16 + cl;
                    float s = acc[r][c][i] * 10.0f;       // 1/TEMPERATURE
                    const size_t off = (size_t)grow * NROWS + gcol;
                    float p = __builtin_nontemporal_load(&pmask[off]);
                    float n = __builtin_nontemporal_load(&nmask[off]);
                    if (grow == gcol) { p = 0.f; n = 0.f; }  // zero diagonal
                    float e  = __expf(s);
                    float ei = __expf(-s);
                    aN += n * e;
                    aS += p * s;
                    aP += p;
                    aQ += p * ei;
                }
                // reduce across the 16 column-lanes of this row
#pragma unroll
                for (int m = 1; m < 16; m <<= 1) {
                    aN += __shfl_xor(aN, m, 64);
                    aS += __shfl_xor(aS, m, 64);
                    aP += __shfl_xor(aP, m, 64);
                    aQ += __shfl_xor(aQ, m, 64);
                }
                if (cl == 0) {
                    atomicAdd(&rowacc[lrow][0], aN);
                    atomicAdd(&rowacc[lrow][1], aS);
                    atomicAdd(&rowacc[lrow][2], aP);
                    atomicAdd(&rowacc[lrow][3], aQ);
                }
            }
        }
    }

    __syncthreads();
    if (t < 128) {
        const int grow = rowBase + t;
        atomicAdd(&negG[grow], rowacc[t][0]);
        atomicAdd(&sG[grow],   rowacc[t][1]);
        atomicAdd(&pG[grow],   rowacc[t][2]);
        atomicAdd(&qG[grow],   rowacc[t][3]);
    }
}

// ---------------------------------------------------------------------------
// Kernel 3: per-row loss assembly + mean
// loss_i = (P*log(neg) - S - eps*neg*Q)/max(P,1);  out = mean_i loss_i
// ---------------------------------------------------------------------------
__global__ __launch_bounds__(1024) void final_k(const float* __restrict__ negG,
        const float* __restrict__ sG, const float* __restrict__ pG,
        const float* __restrict__ qG, float* __restrict__ out) {
    const int t = threadIdx.x;
    float sum = 0.f;
    for (int i = t; i < NROWS; i += 1024) {
        float P = pG[i];
        if (P > 0.f) {
            float neg = negG[i];
            sum += (P * logf(neg) - sG[i] - 1e-6f * neg * qG[i]) / P;
        }
    }
#pragma unroll
    for (int m = 32; m; m >>= 1) sum += __shfl_xor(sum, m, 64);
    __shared__ float wsum[16];
    if ((t & 63) == 0) wsum[t >> 6] = sum;
    __syncthreads();
    if (t < 16) {
        float v = wsum[t];
#pragma unroll
        for (int m = 8; m; m >>= 1) v += __shfl_xor(v, m, 16);
        if (t == 0) out[0] = v / (float)NROWS;
    }
}

// ---------------------------------------------------------------------------
extern "C" void kernel_launch(void* const* d_in, const int* in_sizes, int n_in,
                              void* d_out, int out_size, void* d_ws, size_t ws_size,
                              hipStream_t stream) {
    const float* feat  = (const float*)d_in[0];
    const float* pmask = (const float*)d_in[1];
    const float* nmask = (const float*)d_in[2];
    float* out = (float*)d_out;

    char* ws = (char*)d_ws;
    __hip_bfloat16* fn = (__hip_bfloat16*)ws;                  // 12,582,912 B
    float* negG = (float*)(ws + (size_t)NROWS * DDIM * 2);
    float* sG = negG + NROWS;
    float* pG = sG + NROWS;
    float* qG = pG + NROWS;

    // ws is re-poisoned to 0xAA before every launch -> zero the accumulators
    hipMemsetAsync(negG, 0, 4 * NROWS * sizeof(float), stream);

    normalize_k<<<NROWS, 256, 0, stream>>>(feat, fn);

    dim3 grid(16, 64);   // 16 col-chunks x 64 row-tiles
    ntxent_main<<<grid, 256, 0, stream>>>(fn, pmask, nmask, negG, sG, pG, qG);

    final_k<<<1, 1024, 0, stream>>>(negG, sG, pG, qG, out);
}

// Round 2
// 745.064 us; speedup vs baseline: 1.1387x; 1.1387x over previous
//
#include <hip/hip_runtime.h>
#include <hip/hip_bf16.h>

#define NROWS 8192
#define DDIM 768

typedef short short8 __attribute__((ext_vector_type(8)));   // 8 x bf16 (4 VGPRs)
typedef float floatx4 __attribute__((ext_vector_type(4)));  // MFMA C/D
typedef unsigned long long u64;
typedef u64 u64x4 __attribute__((ext_vector_type(4)));      // 32B packed-mask chunk

// ---------------------------------------------------------------------------
// Kernel 1: row-normalize features (fp32 in) -> bf16 normalized rows
// ---------------------------------------------------------------------------
__global__ __launch_bounds__(256) void normalize_k(const float* __restrict__ f,
                                                   __hip_bfloat16* __restrict__ fn) {
    const int row = blockIdx.x;
    const int t = threadIdx.x;
    const float* fr = f + (size_t)row * DDIM;
    float v0 = fr[t];
    float v1 = fr[t + 256];
    float v2 = fr[t + 512];
    float ss = v0 * v0 + v1 * v1 + v2 * v2;
#pragma unroll
    for (int m = 32; m; m >>= 1) ss += __shfl_xor(ss, m, 64);
    __shared__ float wsum[4];
    if ((t & 63) == 0) wsum[t >> 6] = ss;
    __syncthreads();
    float tot = wsum[0] + wsum[1] + wsum[2] + wsum[3];
    float inv = 1.0f / fmaxf(sqrtf(tot), 1e-8f);
    __hip_bfloat16* o = fn + (size_t)row * DDIM;
    o[t]       = __float2bfloat16(v0 * inv);
    o[t + 256] = __float2bfloat16(v1 * inv);
    o[t + 512] = __float2bfloat16(v2 * inv);
}

// ---------------------------------------------------------------------------
// Kernel 2: pack masks to bits + per-row positive count (diag excluded).
// Layout: word[(row*32+g)*4 + k] bit L = mask[row][256g + 4L + k] != 0.
// This matches the epilogue's fragment order: col offset o=64a+16mf+4q+reg
// -> k=reg, L=16a+4mf+q. One wave per row; float4 loads, __ballot packs.
// ---------------------------------------------------------------------------
__global__ __launch_bounds__(256) void pack_k(const float* __restrict__ pm,
                                              const float* __restrict__ nm,
                                              u64* __restrict__ pmw,
                                              u64* __restrict__ nmw,
                                              float* __restrict__ pG) {
    const int lane = threadIdx.x & 63;
    const int wv = threadIdx.x >> 6;
    const int row = blockIdx.x * 4 + wv;
    const float4* pr = (const float4*)(pm + (size_t)row * NROWS);
    const float4* nr = (const float4*)(nm + (size_t)row * NROWS);
    const int dg = row >> 8;                       // superblock holding diag
    const u64 dclear = ~(1ull << ((row & 255) >> 2));
    int pc = 0;
    for (int g = 0; g < 32; ++g) {
        float4 pv = pr[(size_t)g * 64 + lane];
        float4 nv = nr[(size_t)g * 64 + lane];
        u64 pb0 = __ballot(pv.x != 0.f), pb1 = __ballot(pv.y != 0.f);
        u64 pb2 = __ballot(pv.z != 0.f), pb3 = __ballot(pv.w != 0.f);
        u64 nb0 = __ballot(nv.x != 0.f), nb1 = __ballot(nv.y != 0.f);
        u64 nb2 = __ballot(nv.z != 0.f), nb3 = __ballot(nv.w != 0.f);
        if (g == dg) {                             // zero the diagonal bit
            const int dk = row & 3;
            if (dk == 0) { pb0 &= dclear; nb0 &= dclear; }
            else if (dk == 1) { pb1 &= dclear; nb1 &= dclear; }
            else if (dk == 2) { pb2 &= dclear; nb2 &= dclear; }
            else { pb3 &= dclear; nb3 &= dclear; }
        }
        pc += __popcll(pb0) + __popcll(pb1) + __popcll(pb2) + __popcll(pb3);
        const size_t wi = ((size_t)row * 32 + g) * 4;
        if (lane == 0) *(u64x4*)(pmw + wi) = (u64x4){pb0, pb1, pb2, pb3};
        else if (lane == 1) *(u64x4*)(nmw + wi) = (u64x4){nb0, nb1, nb2, nb3};
    }
    if (lane == 0) pG[row] = (float)pc;
}

// ---------------------------------------------------------------------------
// Kernel 3: bf16 GEMM (s = 10 * fn fn^T) + bit-masked row reductions.
// Operands swapped vs a plain GEMM: A-frag = j rows (cols of s), B-frag =
// i rows, so D: n=lane&15 -> i, m=q*4+reg -> j. The reduction over j is
// 3 in-lane adds + 2 shuffles per variable.
// grid = (16 col-chunks, 64 row-tiles), block = 256 (4 waves, wn x wm = 2x2).
// ---------------------------------------------------------------------------
__global__ __launch_bounds__(256) void ntxent_main(
        const __hip_bfloat16* __restrict__ fn,
        const u64* __restrict__ pmw, const u64* __restrict__ nmw,
        float* __restrict__ negG, float* __restrict__ sG,
        float* __restrict__ qG) {
    __shared__ __hip_bfloat16 Is[128 * 32];   // i-rows tile (8 KB)
    __shared__ __hip_bfloat16 Js[128 * 32];   // j-rows tile (8 KB)
    __shared__ float rowacc[128][4];          // N, S, Q (+pad)

    const int t = threadIdx.x;
    const int lane = t & 63;
    const int wv = t >> 6;
    const int wm = wv & 1;           // wave's j-half (0..1)
    const int wn = wv >> 1;          // wave's i-half (0..1)
    const int q  = lane >> 4;
    const int cl = lane & 15;
    const int rowBase  = blockIdx.y * 128;
    const int colChunk = blockIdx.x * 512;

    if (t < 128) { rowacc[t][0] = 0.f; rowacc[t][1] = 0.f; rowacc[t][2] = 0.f; }

    const int sRow = t >> 2;          // staging: 16B per thread, contiguous
    const int sCol = (t & 3) * 8;

    for (int j2 = 0; j2 < 4; ++j2) {
        const int colBase = colChunk + j2 * 128;
        floatx4 acc[4][4];            // [mf (j)][nf (i)]
#pragma unroll
        for (int mf = 0; mf < 4; ++mf)
#pragma unroll
            for (int nf = 0; nf < 4; ++nf)
                acc[mf][nf] = (floatx4){0.f, 0.f, 0.f, 0.f};

        for (int k0 = 0; k0 < DDIM; k0 += 32) {
            __syncthreads();
#pragma unroll
            for (int it = 0; it < 2; ++it) {
                const int rr = sRow + it * 64;
                const __hip_bfloat16* ga = fn + (size_t)(rowBase + rr) * DDIM + k0 + sCol;
                const __hip_bfloat16* gb = fn + (size_t)(colBase + rr) * DDIM + k0 + sCol;
                __builtin_amdgcn_global_load_lds(
                    (const __attribute__((address_space(1))) void*)ga,
                    (__attribute__((address_space(3))) void*)&Is[rr * 32 + sCol], 16, 0, 0);
                __builtin_amdgcn_global_load_lds(
                    (const __attribute__((address_space(1))) void*)gb,
                    (__attribute__((address_space(3))) void*)&Js[rr * 32 + sCol], 16, 0, 0);
            }
            __syncthreads();

            short8 jf[4], if_[4];
#pragma unroll
            for (int mf = 0; mf < 4; ++mf)
                jf[mf] = *(const short8*)&Js[(wm * 64 + mf * 16 + cl) * 32 + q * 8];
#pragma unroll
            for (int nf = 0; nf < 4; ++nf)
                if_[nf] = *(const short8*)&Is[(wn * 64 + nf * 16 + cl) * 32 + q * 8];
#pragma unroll
            for (int mf = 0; mf < 4; ++mf)
#pragma unroll
                for (int nf = 0; nf < 4; ++nf)
                    acc[mf][nf] = __builtin_amdgcn_mfma_f32_16x16x32_bf16(
                        jf[mf], if_[nf], acc[mf][nf], 0, 0, 0);
        }

        // ---- epilogue: D[m=j][n=i]; j = colBase+wm*64+mf*16+q*4+reg,
        //                              i = rowBase+wn*64+nf*16+cl
        const int col64 = colBase + wm * 64;
        const int g = col64 >> 8;                 // 256-col superblock
        const int a = (col64 >> 6) & 3;           // 64-col slot in superblock
#pragma unroll
        for (int nf = 0; nf < 4; ++nf) {
            const int lrow = wn * 64 + nf * 16 + cl;
            const size_t mbase = ((size_t)(rowBase + lrow) * 32 + g) * 4;
            u64x4 pw = *(const u64x4*)(pmw + mbase);
            u64x4 nw = *(const u64x4*)(nmw + mbase);
            float aN = 0.f, aS = 0.f, aQ = 0.f;
#pragma unroll
            for (int mf = 0; mf < 4; ++mf) {
                const int sh = a * 16 + mf * 4 + q;
#pragma unroll
                for (int reg = 0; reg < 4; ++reg) {
                    float s = acc[mf][nf][reg] * 10.0f;     // 1/TEMPERATURE
                    float e  = __expf(s);
                    float ei = __expf(-s);
                    float pb = (float)((pw[reg] >> sh) & 1);
                    float nb = (float)((nw[reg] >> sh) & 1);
                    aN = fmaf(nb, e, aN);
                    aS = fmaf(pb, s, aS);
                    aQ = fmaf(pb, ei, aQ);
                }
            }
            aN += __shfl_xor(aN, 16, 64);  aN += __shfl_xor(aN, 32, 64);
            aS += __shfl_xor(aS, 16, 64);  aS += __shfl_xor(aS, 32, 64);
            aQ += __shfl_xor(aQ, 16, 64);  aQ += __shfl_xor(aQ, 32, 64);
            if (q == 0) {
                atomicAdd(&rowacc[lrow][0], aN);
                atomicAdd(&rowacc[lrow][1], aS);
                atomicAdd(&rowacc[lrow][2], aQ);
            }
        }
    }

    __syncthreads();
    if (t < 128) {
        const int grow = rowBase + t;
        atomicAdd(&negG[grow], rowacc[t][0]);
        atomicAdd(&sG[grow],   rowacc[t][1]);
        atomicAdd(&qG[grow],   rowacc[t][2]);
    }
}

// ---------------------------------------------------------------------------
// Kernel 4: per-row loss assembly + mean
// loss_i = (P*log(neg) - S - eps*neg*Q)/P (P>0 else 0);  out = mean
// ---------------------------------------------------------------------------
__global__ __launch_bounds__(1024) void final_k(const float* __restrict__ negG,
        const float* __restrict__ sG, const float* __restrict__ pG,
        const float* __restrict__ qG, float* __restrict__ out) {
    const int t = threadIdx.x;
    float sum = 0.f;
    for (int i = t; i < NROWS; i += 1024) {
        float P = pG[i];
        if (P > 0.f) {
            float neg = negG[i];
            sum += (P * logf(neg) - sG[i] - 1e-6f * neg * qG[i]) / P;
        }
    }
#pragma unroll
    for (int m = 32; m; m >>= 1) sum += __shfl_xor(sum, m, 64);
    __shared__ float wsum[16];
    if ((t & 63) == 0) wsum[t >> 6] = sum;
    __syncthreads();
    if (t < 16) {
        float v = wsum[t];
#pragma unroll
        for (int m = 8; m; m >>= 1) v += __shfl_xor(v, m, 16);
        if (t == 0) out[0] = v / (float)NROWS;
    }
}

// ---------------------------------------------------------------------------
extern "C" void kernel_launch(void* const* d_in, const int* in_sizes, int n_in,
                              void* d_out, int out_size, void* d_ws, size_t ws_size,
                              hipStream_t stream) {
    const float* feat  = (const float*)d_in[0];
    const float* pmask = (const float*)d_in[1];
    const float* nmask = (const float*)d_in[2];
    float* out = (float*)d_out;

    char* ws = (char*)d_ws;
    __hip_bfloat16* fn = (__hip_bfloat16*)ws;                    // 12,582,912 B
    u64* pmw = (u64*)(ws + 12582912);                            //  8,388,608 B
    u64* nmw = (u64*)(ws + 12582912 + 8388608);                  //  8,388,608 B
    float* negG = (float*)(ws + 12582912 + 2 * 8388608);
    float* sG = negG + NROWS;
    float* qG = sG + NROWS;
    float* pG = qG + NROWS;

    // zero the three GEMM-side accumulators (pG fully written by pack_k)
    hipMemsetAsync(negG, 0, 3 * NROWS * sizeof(float), stream);

    normalize_k<<<NROWS, 256, 0, stream>>>(feat, fn);
    pack_k<<<NROWS / 4, 256, 0, stream>>>(pmask, nmask, pmw, nmw, pG);

    dim3 grid(16, 64);   // 16 col-chunks x 64 row-tiles
    ntxent_main<<<grid, 256, 0, stream>>>(fn, pmw, nmw, negG, sG, qG);

    final_k<<<1, 1024, 0, stream>>>(negG, sG, pG, qG, out);
}